// Round 3
// baseline (69.013 us; speedup 1.0000x reference)
//
#include <hip/hip_runtime.h>

typedef __attribute__((ext_vector_type(8))) short bf16x8;
typedef __attribute__((ext_vector_type(4))) float f32x4;

__device__ __forceinline__ unsigned short f2bf(float f) {
  unsigned int u = __float_as_uint(f);
  return (unsigned short)((u + 0x7fffu + ((u >> 16) & 1u)) >> 16);  // RNE
}

__device__ __forceinline__ void gload_lds16(const void* g, void* l) {
  __builtin_amdgcn_global_load_lds((const __attribute__((address_space(1))) void*)g,
                                   (__attribute__((address_space(3))) void*)l,
                                   16, 0, 0);
}

// Cast x, U, V fp32 -> bf16 in one grid-stride pass (float4 / ushort4 vectorized).
__global__ void cast3(const float4* __restrict__ x, const float4* __restrict__ U,
                      const float4* __restrict__ V, ushort4* __restrict__ xb,
                      ushort4* __restrict__ Ub, ushort4* __restrict__ Vb) {
  const int NX = 4096 * 4096 / 4;  // 4194304
  const int NU = 256 * 4096 / 4;   // 262144 (U and V same elem count)
  int i = blockIdx.x * blockDim.x + threadIdx.x;
  int stride = gridDim.x * blockDim.x;
  for (; i < NX + 2 * NU; i += stride) {
    const float4* s; ushort4* d; int j;
    if (i < NX)           { s = x; d = xb; j = i; }
    else if (i < NX + NU) { s = U; d = Ub; j = i - NX; }
    else                  { s = V; d = Vb; j = i - NX - NU; }
    float4 v = s[j];
    ushort4 o;
    o.x = f2bf(v.x); o.y = f2bf(v.y); o.z = f2bf(v.z); o.w = f2bf(v.w);
    d[j] = o;
  }
}

// NT GEMM: C[m,n] = sum_k A[m,k]*B[n,k]  (both operands row-major, K contiguous)
// 256 threads = 4 waves in 2x2 grid; wave tile = (MREP*16) x (NREP*16).
// BM = 32*MREP, BN = 32*NREP. BK = 32. global_load_lds width-16 staging,
// double-buffered LDS, one barrier per K-step.
template <int MREP, int NREP, bool BIAS>
__global__ __launch_bounds__(256)
void gemm_nt(const unsigned short* __restrict__ A,
             const unsigned short* __restrict__ B,
             const float* __restrict__ bias,
             float* __restrict__ C,
             int lda, int ldb, int ldc,
             int nkt, int kChunk, long long splitStride) {
  constexpr int BM = 32 * MREP;
  constexpr int BN = 32 * NREP;
  constexpr int ISS_A = BM / 64;  // 4KB LDS per issue (256 thr x 16B)
  constexpr int ISS_B = BN / 64;

  __shared__ unsigned short sA[2][BM * 32];
  __shared__ unsigned short sB[2][BN * 32];

  const int tid = threadIdx.x;
  const int l = tid & 63;
  const int w = tid >> 6;
  const int wm = (w >> 1) * (MREP * 16);
  const int wn = (w & 1) * (NREP * 16);
  const int rm = blockIdx.x * BM;
  const int rn = blockIdx.y * BN;
  const int k0base = blockIdx.z * kChunk;

  const int lr = l & 15;         // fragment row (A: M idx, B: N idx)
  const int lc8 = (l >> 4) * 8;  // fragment k offset (contiguous 8 bf16)

  auto stage = [&](int kt, int buf) {
    const int k0 = k0base + kt * 32;
#pragma unroll
    for (int is = 0; is < ISS_A; ++is) {
      int eo = is * 2048 + tid * 8;       // element offset in [BM][32] tile
      int r = eo >> 5, c = eo & 31;
      gload_lds16(A + (long long)(rm + r) * lda + k0 + c, &sA[buf][eo]);
    }
#pragma unroll
    for (int is = 0; is < ISS_B; ++is) {
      int eo = is * 2048 + tid * 8;
      int r = eo >> 5, c = eo & 31;
      gload_lds16(B + (long long)(rn + r) * ldb + k0 + c, &sB[buf][eo]);
    }
  };

  f32x4 acc[MREP][NREP] = {};

  stage(0, 0);
  for (int kt = 0; kt < nkt; ++kt) {
    __syncthreads();  // drains vmcnt: tile kt resident; prev compute done
    if (kt + 1 < nkt) stage(kt + 1, (kt + 1) & 1);
    const unsigned short* a0 = sA[kt & 1];
    const unsigned short* b0 = sB[kt & 1];
    bf16x8 af[MREP], bfr[NREP];
#pragma unroll
    for (int m = 0; m < MREP; ++m)
      af[m] = *(const bf16x8*)&a0[(wm + m * 16 + lr) * 32 + lc8];
#pragma unroll
    for (int n = 0; n < NREP; ++n)
      bfr[n] = *(const bf16x8*)&b0[(wn + n * 16 + lr) * 32 + lc8];
#pragma unroll
    for (int m = 0; m < MREP; ++m)
#pragma unroll
      for (int n = 0; n < NREP; ++n)
        acc[m][n] = __builtin_amdgcn_mfma_f32_16x16x32_bf16(af[m], bfr[n], acc[m][n], 0, 0, 0);
  }

  // Epilogue. C/D layout: col = lane&15, row = (lane>>4)*4 + reg.
  float* Cb = C + (long long)blockIdx.z * splitStride;
  const int r0 = rm + wm + (l >> 4) * 4;
  const int c0 = rn + wn + lr;
#pragma unroll
  for (int n = 0; n < NREP; ++n) {
    const int cc = c0 + n * 16;
    const float badd = BIAS ? bias[cc] : 0.0f;
#pragma unroll
    for (int m = 0; m < MREP; ++m) {
#pragma unroll
      for (int i = 0; i < 4; ++i)
        Cb[(long long)(r0 + m * 16 + i) * ldc + cc] = acc[m][n][i] + badd;
    }
  }
}

// Sum KSPLIT=4 fp32 partials -> bf16 t
__global__ void reduce4(const float4* __restrict__ P, ushort4* __restrict__ t) {
  const int S = 4096 * 256 / 4;  // 262144 float4 per split slice
  int i = blockIdx.x * 256 + threadIdx.x;
  float4 a = P[i], b = P[i + S], c = P[i + 2 * S], d = P[i + 3 * S];
  ushort4 o;
  o.x = f2bf(a.x + b.x + c.x + d.x);
  o.y = f2bf(a.y + b.y + c.y + d.y);
  o.z = f2bf(a.z + b.z + c.z + d.z);
  o.w = f2bf(a.w + b.w + c.w + d.w);
  t[i] = o;
}

extern "C" void kernel_launch(void* const* d_in, const int* in_sizes, int n_in,
                              void* d_out, int out_size, void* d_ws, size_t ws_size,
                              hipStream_t stream) {
  const float* x    = (const float*)d_in[0];  // [4096,4096]
  const float* U    = (const float*)d_in[1];  // [256,4096]
  const float* V    = (const float*)d_in[2];  // [4096,256]
  const float* bias = (const float*)d_in[3];  // [4096]
  float* out = (float*)d_out;                 // [4096,4096] fp32

  // Workspace layout (54 MB total):
  //  [0,16MB)   P: fp32 split-K partials [4][4096][256]
  //  [16,18MB)  t bf16 [4096][256]
  //  [18,50MB)  x bf16 [4096][4096]
  //  [50,52MB)  U bf16 [256][4096]
  //  [52,54MB)  V bf16 [4096][256]
  char* ws = (char*)d_ws;
  float* P            = (float*)ws;
  unsigned short* tb  = (unsigned short*)(ws + (16u << 20));
  unsigned short* xb  = (unsigned short*)(ws + (18u << 20));
  unsigned short* Ub  = (unsigned short*)(ws + (50u << 20));
  unsigned short* Vb  = (unsigned short*)(ws + (52u << 20));

  cast3<<<2048, 256, 0, stream>>>((const float4*)x, (const float4*)U, (const float4*)V,
                                  (ushort4*)xb, (ushort4*)Ub, (ushort4*)Vb);

  // GEMM1: t_partial[s] = x[:, s*1024:(s+1)*1024] @ U[:, s*1024:(s+1)*1024]^T
  // BM=64, BN=128, grid 64x2x4 = 512 blocks
  dim3 g1(4096 / 64, 256 / 128, 4);
  gemm_nt<2, 4, false><<<g1, 256, 0, stream>>>(xb, Ub, nullptr, P,
                                               4096, 4096, 256,
                                               /*nkt=*/32, /*kChunk=*/1024,
                                               (long long)4096 * 256);

  reduce4<<<(4096 * 256 / 4) / 256, 256, 0, stream>>>((const float4*)P, (ushort4*)tb);

  // GEMM2: out = t @ V^T + bias. BM=BN=128, grid 32x32.
  dim3 g2(4096 / 128, 4096 / 128, 1);
  gemm_nt<4, 4, true><<<g2, 256, 0, stream>>>(tb, Vb, bias, out,
                                              256, 256, 4096,
                                              /*nkt=*/8, /*kChunk=*/0, 0);
}

// Round 4
// 67.943 us; speedup vs baseline: 1.0157x; 1.0157x over previous
//
#include <hip/hip_runtime.h>

typedef __attribute__((ext_vector_type(8))) short bf16x8;
typedef __attribute__((ext_vector_type(4))) float f32x4;

__device__ __forceinline__ unsigned short f2bf(float f) {
  unsigned int u = __float_as_uint(f);
  return (unsigned short)((u + 0x7fffu + ((u >> 16) & 1u)) >> 16);  // RNE
}

__device__ __forceinline__ void gload_lds16(const void* g, void* l) {
  __builtin_amdgcn_global_load_lds((const __attribute__((address_space(1))) void*)g,
                                   (__attribute__((address_space(3))) void*)l,
                                   16, 0, 0);
}

// Cast U, V fp32 -> bf16 (12 MB total traffic, ~2.5us).
__global__ void castUV(const float4* __restrict__ U, const float4* __restrict__ V,
                       ushort4* __restrict__ Ub, ushort4* __restrict__ Vb) {
  const int NU = 256 * 4096 / 4;  // 262144 float4 each
  int i = blockIdx.x * 256 + threadIdx.x;
  const float4* s; ushort4* d; int j;
  if (i < NU) { s = U; d = Ub; j = i; }
  else        { s = V; d = Vb; j = i - NU; }
  float4 v = s[j];
  ushort4 o;
  o.x = f2bf(v.x); o.y = f2bf(v.y); o.z = f2bf(v.z); o.w = f2bf(v.w);
  d[j] = o;
}

// NT GEMM: C[m,n] = sum_k A[m,k]*B[n,k]  (row-major, K contiguous).
// 256 threads = 4 waves in 2x2 grid; wave tile = (MREP*16) x (NREP*16).
// BM = 32*MREP, BN = 32*NREP, BK = 32. Double-buffered LDS, 1 barrier/K-step.
// B staged via global_load_lds (bf16 input). A staged either via global_load_lds
// (bf16) or, when AFP32, reg-staged fp32 -> RNE bf16 -> ds_write (fused cast).
template <int MREP, int NREP, bool BIAS, bool AFP32>
__global__ __launch_bounds__(256)
void gemm_nt(const void* __restrict__ Ap,
             const unsigned short* __restrict__ B,
             const float* __restrict__ bias,
             float* __restrict__ C,
             int lda, int ldb, int ldc,
             int nkt, int kChunk, long long splitStride) {
  constexpr int BM = 32 * MREP;
  constexpr int BN = 32 * NREP;
  constexpr int ISS_A = BM / 64;   // gload_lds issues for A (bf16 path)
  constexpr int ISS_B = BN / 64;

  __shared__ unsigned short sA[2][BM * 32];
  __shared__ unsigned short sB[2][BN * 32];

  const int tid = threadIdx.x;
  const int l = tid & 63;
  const int w = tid >> 6;
  const int wm = (w >> 1) * (MREP * 16);
  const int wn = (w & 1) * (NREP * 16);
  const int rm = blockIdx.x * BM;
  const int rn = blockIdx.y * BN;
  const int k0base = blockIdx.z * kChunk;

  const int lr = l & 15;         // fragment row (A: M idx, B: N idx)
  const int lc8 = (l >> 4) * 8;  // fragment k offset (contiguous 8 bf16)

  auto stage = [&](int kt, int buf) {
    const int k0 = k0base + kt * 32;
    if constexpr (AFP32) {
      const float* A32 = (const float*)Ap;
      constexpr int EPT = BM * 32 / 256;  // elems per thread (4 or 8)
      const int eo = tid * EPT;
      const int r = eo >> 5, c = eo & 31;
      const float* src = A32 + (long long)(rm + r) * lda + k0 + c;
      if constexpr (EPT == 4) {
        float4 v = *(const float4*)src;
        ushort4 o;
        o.x = f2bf(v.x); o.y = f2bf(v.y); o.z = f2bf(v.z); o.w = f2bf(v.w);
        *(ushort4*)&sA[buf][eo] = o;
      } else {
        float4 v0 = *(const float4*)src;
        float4 v1 = *(const float4*)(src + 4);
        ushort4 o0, o1;
        o0.x = f2bf(v0.x); o0.y = f2bf(v0.y); o0.z = f2bf(v0.z); o0.w = f2bf(v0.w);
        o1.x = f2bf(v1.x); o1.y = f2bf(v1.y); o1.z = f2bf(v1.z); o1.w = f2bf(v1.w);
        *(ushort4*)&sA[buf][eo] = o0;
        *(ushort4*)&sA[buf][eo + 4] = o1;
      }
    } else {
      const unsigned short* A = (const unsigned short*)Ap;
#pragma unroll
      for (int is = 0; is < ISS_A; ++is) {
        int eo = is * 2048 + tid * 8;
        int r = eo >> 5, c = eo & 31;
        gload_lds16(A + (long long)(rm + r) * lda + k0 + c, &sA[buf][eo]);
      }
    }
#pragma unroll
    for (int is = 0; is < ISS_B; ++is) {
      int eo = is * 2048 + tid * 8;
      int r = eo >> 5, c = eo & 31;
      gload_lds16(B + (long long)(rn + r) * ldb + k0 + c, &sB[buf][eo]);
    }
  };

  f32x4 acc[MREP][NREP] = {};

  stage(0, 0);
  for (int kt = 0; kt < nkt; ++kt) {
    __syncthreads();  // drains vmcnt+lgkmcnt: tile kt resident; prev reads done
    if (kt + 1 < nkt) stage(kt + 1, (kt + 1) & 1);
    const unsigned short* a0 = sA[kt & 1];
    const unsigned short* b0 = sB[kt & 1];
    bf16x8 af[MREP], bfr[NREP];
#pragma unroll
    for (int m = 0; m < MREP; ++m)
      af[m] = *(const bf16x8*)&a0[(wm + m * 16 + lr) * 32 + lc8];
#pragma unroll
    for (int n = 0; n < NREP; ++n)
      bfr[n] = *(const bf16x8*)&b0[(wn + n * 16 + lr) * 32 + lc8];
#pragma unroll
    for (int m = 0; m < MREP; ++m)
#pragma unroll
      for (int n = 0; n < NREP; ++n)
        acc[m][n] = __builtin_amdgcn_mfma_f32_16x16x32_bf16(af[m], bfr[n], acc[m][n], 0, 0, 0);
  }

  // Epilogue. C/D layout: col = lane&15, row = (lane>>4)*4 + reg.
  float* Cb = C + (long long)blockIdx.z * splitStride;
  const int r0 = rm + wm + (l >> 4) * 4;
  const int c0 = rn + wn + lr;
#pragma unroll
  for (int n = 0; n < NREP; ++n) {
    const int cc = c0 + n * 16;
    const float badd = BIAS ? bias[cc] : 0.0f;
#pragma unroll
    for (int m = 0; m < MREP; ++m) {
#pragma unroll
      for (int i = 0; i < 4; ++i)
        Cb[(long long)(r0 + m * 16 + i) * ldc + cc] = acc[m][n][i] + badd;
    }
  }
}

// Sum 8 fp32 split-K partial slices -> bf16 t
__global__ void reduce8(const float4* __restrict__ P, ushort4* __restrict__ t) {
  const int S = 4096 * 256 / 4;  // 262144 float4 per slice
  int i = blockIdx.x * 256 + threadIdx.x;
  float4 s = P[i];
#pragma unroll
  for (int z = 1; z < 8; ++z) {
    float4 v = P[i + z * S];
    s.x += v.x; s.y += v.y; s.z += v.z; s.w += v.w;
  }
  ushort4 o;
  o.x = f2bf(s.x); o.y = f2bf(s.y); o.z = f2bf(s.z); o.w = f2bf(s.w);
  t[i] = o;
}

extern "C" void kernel_launch(void* const* d_in, const int* in_sizes, int n_in,
                              void* d_out, int out_size, void* d_ws, size_t ws_size,
                              hipStream_t stream) {
  const float* x    = (const float*)d_in[0];  // [4096,4096]
  const float* U    = (const float*)d_in[1];  // [256,4096]
  const float* V    = (const float*)d_in[2];  // [4096,256]
  const float* bias = (const float*)d_in[3];  // [4096]
  float* out = (float*)d_out;                 // [4096,4096] fp32

  // Workspace layout (38 MB):
  //  [0,32MB)   P: fp32 split-K partials [8][4096][256]
  //  [32,34MB)  t bf16 [4096][256]
  //  [34,36MB)  U bf16 [256][4096]
  //  [36,38MB)  V bf16 [4096][256]
  char* ws = (char*)d_ws;
  float* P            = (float*)ws;
  unsigned short* tb  = (unsigned short*)(ws + (32u << 20));
  unsigned short* Ub  = (unsigned short*)(ws + (34u << 20));
  unsigned short* Vb  = (unsigned short*)(ws + (36u << 20));

  castUV<<<2048, 256, 0, stream>>>((const float4*)U, (const float4*)V,
                                   (ushort4*)Ub, (ushort4*)Vb);

  // GEMM1: P[z] = x[:, z*512:(z+1)*512] (fp32, cast fused) @ U[:, same]^T
  // BM=32, BN=256, grid 128x1x8 = 1024 blocks (4/CU), kChunk=512, 16 K-steps.
  dim3 g1(4096 / 32, 1, 8);
  gemm_nt<1, 8, false, true><<<g1, 256, 0, stream>>>(x, Ub, nullptr, P,
                                                     4096, 4096, 256,
                                                     /*nkt=*/16, /*kChunk=*/512,
                                                     (long long)4096 * 256);

  reduce8<<<(4096 * 256 / 4) / 256, 256, 0, stream>>>((const float4*)P, (ushort4*)tb);

  // GEMM2: out = t @ V^T + bias. BM=BN=128, grid 32x32.
  dim3 g2(4096 / 128, 4096 / 128, 1);
  gemm_nt<4, 4, true, false><<<g2, 256, 0, stream>>>(tb, Vb, bias, out,
                                                     256, 256, 4096,
                                                     /*nkt=*/8, /*kChunk=*/0, 0);
}

// Round 5
// 60.843 us; speedup vs baseline: 1.1343x; 1.1167x over previous
//
#include <hip/hip_runtime.h>

typedef __attribute__((ext_vector_type(8))) short bf16x8;
typedef __attribute__((ext_vector_type(4))) float f32x4;

__device__ __forceinline__ unsigned short f2bf(float f) {
  unsigned int u = __float_as_uint(f);
  return (unsigned short)((u + 0x7fffu + ((u >> 16) & 1u)) >> 16);  // RNE
}

__device__ __forceinline__ float bf2f(unsigned short s) {
  return __uint_as_float(((unsigned int)s) << 16);
}

__device__ __forceinline__ void gload_lds16(const void* g, void* l) {
  __builtin_amdgcn_global_load_lds((const __attribute__((address_space(1))) void*)g,
                                   (__attribute__((address_space(3))) void*)l,
                                   16, 0, 0);
}

// Cast U, V fp32 -> bf16 (12 MB total traffic, ~2.5us).
__global__ void castUV(const float4* __restrict__ U, const float4* __restrict__ V,
                       ushort4* __restrict__ Ub, ushort4* __restrict__ Vb) {
  const int NU = 256 * 4096 / 4;  // 262144 float4 each
  int i = blockIdx.x * 256 + threadIdx.x;
  const float4* s; ushort4* d; int j;
  if (i < NU) { s = U; d = Ub; j = i; }
  else        { s = V; d = Vb; j = i - NU; }
  float4 v = s[j];
  ushort4 o;
  o.x = f2bf(v.x); o.y = f2bf(v.y); o.z = f2bf(v.z); o.w = f2bf(v.w);
  d[j] = o;
}

// NT GEMM: C[m,n] = sum_k A[m,k]*B[n,k]  (row-major, K contiguous).
// 256 threads = 4 waves in 2x2 grid; wave tile = (MREP*16) x (NREP*16).
// BM = 32*MREP, BN = 32*NREP, BK = 32. Double-buffered LDS, 1 barrier/K-step.
// B staged via global_load_lds (bf16). A staged via global_load_lds (bf16) or,
// when AFP32, reg-staged fp32 -> RNE bf16 -> ds_write (fused cast).
// OUT_BF16 selects bf16 C output (split-K partials), else fp32 (+bias).
template <int MREP, int NREP, bool BIAS, bool AFP32, bool OUT_BF16>
__global__ __launch_bounds__(256)
void gemm_nt(const void* __restrict__ Ap,
             const unsigned short* __restrict__ B,
             const float* __restrict__ bias,
             void* __restrict__ Cv,
             int lda, int ldb, int ldc,
             int nkt, int kChunk, long long splitStride) {
  constexpr int BM = 32 * MREP;
  constexpr int BN = 32 * NREP;
  constexpr int ISS_A = BM / 64;
  constexpr int ISS_B = BN / 64;

  __shared__ unsigned short sA[2][BM * 32];
  __shared__ unsigned short sB[2][BN * 32];

  const int tid = threadIdx.x;
  const int l = tid & 63;
  const int w = tid >> 6;
  const int wm = (w >> 1) * (MREP * 16);
  const int wn = (w & 1) * (NREP * 16);
  const int rm = blockIdx.x * BM;
  const int rn = blockIdx.y * BN;
  const int k0base = blockIdx.z * kChunk;

  const int lr = l & 15;         // fragment row (A: M idx, B: N idx)
  const int lc8 = (l >> 4) * 8;  // fragment k offset (contiguous 8 bf16)

  auto stage = [&](int kt, int buf) {
    const int k0 = k0base + kt * 32;
    // B first: get async gload_lds in flight under A's load+cvt.
#pragma unroll
    for (int is = 0; is < ISS_B; ++is) {
      int eo = is * 2048 + tid * 8;
      int r = eo >> 5, c = eo & 31;
      gload_lds16(B + (long long)(rn + r) * ldb + k0 + c, &sB[buf][eo]);
    }
    if constexpr (AFP32) {
      const float* A32 = (const float*)Ap;
      constexpr int EPT = BM * 32 / 256;  // 8 for BM=64
      const int eo = tid * EPT;
      const int r = eo >> 5, c = eo & 31;
      const float* src = A32 + (long long)(rm + r) * lda + k0 + c;
      if constexpr (EPT == 4) {
        float4 v = *(const float4*)src;
        ushort4 o;
        o.x = f2bf(v.x); o.y = f2bf(v.y); o.z = f2bf(v.z); o.w = f2bf(v.w);
        *(ushort4*)&sA[buf][eo] = o;
      } else {
        float4 v0 = *(const float4*)src;
        float4 v1 = *(const float4*)(src + 4);
        ushort4 o0, o1;
        o0.x = f2bf(v0.x); o0.y = f2bf(v0.y); o0.z = f2bf(v0.z); o0.w = f2bf(v0.w);
        o1.x = f2bf(v1.x); o1.y = f2bf(v1.y); o1.z = f2bf(v1.z); o1.w = f2bf(v1.w);
        *(ushort4*)&sA[buf][eo] = o0;
        *(ushort4*)&sA[buf][eo + 4] = o1;
      }
    } else {
      const unsigned short* A = (const unsigned short*)Ap;
#pragma unroll
      for (int is = 0; is < ISS_A; ++is) {
        int eo = is * 2048 + tid * 8;
        int r = eo >> 5, c = eo & 31;
        gload_lds16(A + (long long)(rm + r) * lda + k0 + c, &sA[buf][eo]);
      }
    }
  };

  f32x4 acc[MREP][NREP] = {};

  stage(0, 0);
  for (int kt = 0; kt < nkt; ++kt) {
    __syncthreads();  // drains vmcnt+lgkmcnt: tile kt resident; prev reads done
    if (kt + 1 < nkt) stage(kt + 1, (kt + 1) & 1);
    const unsigned short* a0 = sA[kt & 1];
    const unsigned short* b0 = sB[kt & 1];
    bf16x8 af[MREP], bfr[NREP];
#pragma unroll
    for (int m = 0; m < MREP; ++m)
      af[m] = *(const bf16x8*)&a0[(wm + m * 16 + lr) * 32 + lc8];
#pragma unroll
    for (int n = 0; n < NREP; ++n)
      bfr[n] = *(const bf16x8*)&b0[(wn + n * 16 + lr) * 32 + lc8];
#pragma unroll
    for (int m = 0; m < MREP; ++m)
#pragma unroll
      for (int n = 0; n < NREP; ++n)
        acc[m][n] = __builtin_amdgcn_mfma_f32_16x16x32_bf16(af[m], bfr[n], acc[m][n], 0, 0, 0);
  }

  // Epilogue. C/D layout: col = lane&15, row = (lane>>4)*4 + reg.
  const int r0 = rm + wm + (l >> 4) * 4;
  const int c0 = rn + wn + lr;
  if constexpr (OUT_BF16) {
    unsigned short* Cb = (unsigned short*)Cv + (long long)blockIdx.z * splitStride;
#pragma unroll
    for (int n = 0; n < NREP; ++n) {
      const int cc = c0 + n * 16;
#pragma unroll
      for (int m = 0; m < MREP; ++m)
#pragma unroll
        for (int i = 0; i < 4; ++i)
          Cb[(long long)(r0 + m * 16 + i) * ldc + cc] = f2bf(acc[m][n][i]);
    }
  } else {
    float* Cb = (float*)Cv + (long long)blockIdx.z * splitStride;
#pragma unroll
    for (int n = 0; n < NREP; ++n) {
      const int cc = c0 + n * 16;
      const float badd = BIAS ? bias[cc] : 0.0f;
#pragma unroll
      for (int m = 0; m < MREP; ++m)
#pragma unroll
        for (int i = 0; i < 4; ++i)
          Cb[(long long)(r0 + m * 16 + i) * ldc + cc] = acc[m][n][i] + badd;
    }
  }
}

// Sum 8 bf16 split-K partial slices -> bf16 t (fp32 accumulate)
__global__ void reduce8(const ushort4* __restrict__ P, ushort4* __restrict__ t) {
  const int S = 4096 * 256 / 4;  // 262144 ushort4 per slice
  int i = blockIdx.x * 256 + threadIdx.x;
  float sx = 0, sy = 0, sz = 0, sw = 0;
#pragma unroll
  for (int z = 0; z < 8; ++z) {
    ushort4 v = P[i + z * S];
    sx += bf2f(v.x); sy += bf2f(v.y); sz += bf2f(v.z); sw += bf2f(v.w);
  }
  ushort4 o;
  o.x = f2bf(sx); o.y = f2bf(sy); o.z = f2bf(sz); o.w = f2bf(sw);
  t[i] = o;
}

extern "C" void kernel_launch(void* const* d_in, const int* in_sizes, int n_in,
                              void* d_out, int out_size, void* d_ws, size_t ws_size,
                              hipStream_t stream) {
  const float* x    = (const float*)d_in[0];  // [4096,4096]
  const float* U    = (const float*)d_in[1];  // [256,4096]
  const float* V    = (const float*)d_in[2];  // [4096,256]
  const float* bias = (const float*)d_in[3];  // [4096]
  float* out = (float*)d_out;                 // [4096,4096] fp32

  // Workspace layout (22 MB):
  //  [0,16MB)   P: bf16 split-K partials [8][4096][256]
  //  [16,18MB)  t bf16 [4096][256]
  //  [18,20MB)  U bf16 [256][4096]
  //  [20,22MB)  V bf16 [4096][256]
  char* ws = (char*)d_ws;
  unsigned short* P   = (unsigned short*)ws;
  unsigned short* tb  = (unsigned short*)(ws + (16u << 20));
  unsigned short* Ub  = (unsigned short*)(ws + (18u << 20));
  unsigned short* Vb  = (unsigned short*)(ws + (20u << 20));

  castUV<<<2048, 256, 0, stream>>>((const float4*)U, (const float4*)V,
                                   (ushort4*)Ub, (ushort4*)Vb);

  // GEMM1: P[z] = x[:, z*512:(z+1)*512] (fp32, cast fused) @ U[:, same]^T  (bf16 out)
  // BM=64, BN=256 (x streamed once), grid 64x1x8 = 512 blocks, 16 K-steps each.
  dim3 g1(4096 / 64, 1, 8);
  gemm_nt<2, 8, false, true, true><<<g1, 256, 0, stream>>>(
      x, Ub, nullptr, P, 4096, 4096, 256,
      /*nkt=*/16, /*kChunk=*/512, (long long)4096 * 256);

  reduce8<<<(4096 * 256 / 4) / 256, 256, 0, stream>>>((const ushort4*)P, (ushort4*)tb);

  // GEMM2: out = t @ V^T + bias. BM=BN=128, grid 32x32, fp32 out.
  dim3 g2(4096 / 128, 4096 / 128, 1);
  gemm_nt<4, 4, true, false, false><<<g2, 256, 0, stream>>>(
      tb, Vb, bias, out, 256, 256, 4096,
      /*nkt=*/8, /*kChunk=*/0, 0);
}

// Round 6
// 57.056 us; speedup vs baseline: 1.2096x; 1.0664x over previous
//
#include <hip/hip_runtime.h>

typedef __attribute__((ext_vector_type(8))) short bf16x8;
typedef __attribute__((ext_vector_type(4))) float f32x4;

__device__ __forceinline__ unsigned short f2bf(float f) {
  unsigned int u = __float_as_uint(f);
  return (unsigned short)((u + 0x7fffu + ((u >> 16) & 1u)) >> 16);  // RNE
}

__device__ __forceinline__ float bf2f(unsigned short s) {
  return __uint_as_float(((unsigned int)s) << 16);
}

__device__ __forceinline__ void gload_lds16(const void* g, void* l) {
  __builtin_amdgcn_global_load_lds((const __attribute__((address_space(1))) void*)g,
                                   (__attribute__((address_space(3))) void*)l,
                                   16, 0, 0);
}

// Cast U, V fp32 -> bf16 (12 MB total traffic, ~2.5us).
__global__ void castUV(const float4* __restrict__ U, const float4* __restrict__ V,
                       ushort4* __restrict__ Ub, ushort4* __restrict__ Vb) {
  const int NU = 256 * 4096 / 4;  // 262144 float4 each
  int i = blockIdx.x * 256 + threadIdx.x;
  const float4* s; ushort4* d; int j;
  if (i < NU) { s = U; d = Ub; j = i; }
  else        { s = V; d = Vb; j = i - NU; }
  float4 v = s[j];
  ushort4 o;
  o.x = f2bf(v.x); o.y = f2bf(v.y); o.z = f2bf(v.z); o.w = f2bf(v.w);
  d[j] = o;
}

// ---------------------------------------------------------------------------
// GEMM1, deep-pipelined: P[z][m][r] = sum_k x[m, z*512+k] * U[r, z*512+k]
// x fp32 (cast fused), U bf16, P bf16 partials. BM=64, BN=256 (full rank),
// BK=32, NKT=16 steps. 256 threads = 4 waves (2x2), wave tile 32x128,
// 16 MFMA/step/wave.
// Pipeline: A global->reg 4 ahead (rotating 4 reg sets), cvt+ds_write 1 ahead
// (mod-3 sA), B global_load_lds 2 ahead (mod-4 sB). One raw s_barrier/step
// with counted s_waitcnt vmcnt(12) (= 2 stages in flight), never vmcnt(0).
// Clamped (never skipped) issues keep vmcnt counts uniform at every step.
// Race safety: laggard waves are at most 1 barrier behind; pre-barrier writes
// touch sA[(j+1)%3] / sB[(j+2)%4], laggard reads sA[(j-1)%3] / sB[(j-1)%4] —
// disjoint (diff 2 mod 3, diff 3 mod 4).
// ---------------------------------------------------------------------------
template <int NKT>
__global__ __launch_bounds__(256, 2)
void gemm1_pipe(const float* __restrict__ x, const unsigned short* __restrict__ U,
                unsigned short* __restrict__ P) {
  __shared__ unsigned short sA[3][64 * 32];    // 3 x 4 KB
  __shared__ unsigned short sB[4][256 * 32];   // 4 x 16 KB  (total 76 KB)

  const int tid = threadIdx.x;
  const int l = tid & 63;
  const int w = tid >> 6;
  const int wm = (w >> 1) * 32;    // wave M offset (MREP=2)
  const int wn = (w & 1) * 128;    // wave N offset (NREP=8)
  const int rm = blockIdx.x * 64;
  const int k0base = blockIdx.z * (NKT * 32);
  const int lr = l & 15;
  const int lc8 = (l >> 4) * 8;

  // A staging address for this thread: row rm + tid/4, col (tid&3)*8
  const float* xs = x + (long long)(rm + (tid >> 2)) * 4096 + k0base + (tid & 3) * 8;

  float4 ar[4][2];  // rotating A reg sets (compile-time indexed under full unroll)

  auto GA = [&](int j, int slot) {
    const float* s = xs + j * 32;
    ar[slot][0] = *(const float4*)s;
    ar[slot][1] = *(const float4*)(s + 4);
  };
  auto WR = [&](int jbuf, int slot) {  // cvt + ds_write into sA[jbuf%3]
    float4 v0 = ar[slot][0], v1 = ar[slot][1];
    ushort4 o0, o1;
    o0.x = f2bf(v0.x); o0.y = f2bf(v0.y); o0.z = f2bf(v0.z); o0.w = f2bf(v0.w);
    o1.x = f2bf(v1.x); o1.y = f2bf(v1.y); o1.z = f2bf(v1.z); o1.w = f2bf(v1.w);
    ushort4* d = (ushort4*)&sA[jbuf % 3][tid * 8];
    d[0] = o0; d[1] = o1;
  };
  auto GB = [&](int jdata, int jbuf) {  // 4x gload_lds into sB[jbuf%4]
    const int k0 = k0base + jdata * 32;
#pragma unroll
    for (int is = 0; is < 4; ++is) {
      int eo = is * 2048 + tid * 8;
      gload_lds16(U + (long long)(eo >> 5) * 4096 + k0 + (eo & 31),
                  &sB[jbuf % 4][eo]);
    }
  };

  f32x4 acc[2][8] = {};

  // Prologue — issue order mimics steady state: GA0 GA1 GA2 GB0 GA3 GB1, W(0)
  GA(0, 0); GA(1, 1); GA(2, 2);
  GB(0, 0);
  GA(3, 3);
  GB(1, 1);
  WR(0, 0);  // compiler auto-waits GA(0)

#pragma unroll
  for (int j = 0; j < NKT; ++j) {
    // step 1: A loads 4 ahead (clamped — uniform vmcnt counts, data unused at tail)
    GA((j + 4 < NKT) ? (j + 4) : (NKT - 1), (j + 4) & 3);
    // step 2: cvt+write A for j+1 (slot data: at j=NKT-1 garbage into unused buf)
    WR(j + 1, (j + 1) & 3);  // compiler auto-waits the GA feeding this slot
    // step 3: B stage 2 ahead (clamped)
    GB((j + 2 < NKT) ? (j + 2) : (NKT - 1), j + 2);
    // step 4: counted drain — GB(j) & all older complete; ds_writes visible
    asm volatile("s_waitcnt vmcnt(12) lgkmcnt(0)" ::: "memory");
    __builtin_amdgcn_sched_barrier(0);
    __builtin_amdgcn_s_barrier();
    __builtin_amdgcn_sched_barrier(0);
    // step 5: fragments + MFMA (tile j resident in sA[j%3], sB[j%4])
    const unsigned short* a0 = sA[j % 3];
    const unsigned short* b0 = sB[j % 4];
    bf16x8 af[2], bf[8];
#pragma unroll
    for (int m = 0; m < 2; ++m)
      af[m] = *(const bf16x8*)&a0[(wm + m * 16 + lr) * 32 + lc8];
#pragma unroll
    for (int n = 0; n < 8; ++n)
      bf[n] = *(const bf16x8*)&b0[(wn + n * 16 + lr) * 32 + lc8];
#pragma unroll
    for (int m = 0; m < 2; ++m)
#pragma unroll
      for (int n = 0; n < 8; ++n)
        acc[m][n] = __builtin_amdgcn_mfma_f32_16x16x32_bf16(af[m], bf[n], acc[m][n], 0, 0, 0);
  }

  // Epilogue: bf16 partials. C/D layout: col = lane&15, row = (lane>>4)*4 + reg.
  unsigned short* Cb = P + (long long)blockIdx.z * (4096LL * 256);
  const int r0 = rm + wm + (l >> 4) * 4;
  const int c0 = wn + lr;
#pragma unroll
  for (int n = 0; n < 8; ++n) {
    const int cc = c0 + n * 16;
#pragma unroll
    for (int m = 0; m < 2; ++m)
#pragma unroll
      for (int i = 0; i < 4; ++i)
        Cb[(long long)(r0 + m * 16 + i) * 256 + cc] = f2bf(acc[m][n][i]);
  }
}

// ---------------------------------------------------------------------------
// GEMM2 (unchanged from round 5): out = t @ V^T + bias, fp32 out.
// ---------------------------------------------------------------------------
template <int MREP, int NREP>
__global__ __launch_bounds__(256)
void gemm_nt(const unsigned short* __restrict__ A,
             const unsigned short* __restrict__ B,
             const float* __restrict__ bias,
             float* __restrict__ C,
             int lda, int ldb, int ldc, int nkt) {
  constexpr int BM = 32 * MREP;
  constexpr int BN = 32 * NREP;
  constexpr int ISS_A = BM / 64;
  constexpr int ISS_B = BN / 64;

  __shared__ unsigned short sA[2][BM * 32];
  __shared__ unsigned short sB[2][BN * 32];

  const int tid = threadIdx.x;
  const int l = tid & 63;
  const int w = tid >> 6;
  const int wm = (w >> 1) * (MREP * 16);
  const int wn = (w & 1) * (NREP * 16);
  const int rm = blockIdx.x * BM;
  const int rn = blockIdx.y * BN;

  const int lr = l & 15;
  const int lc8 = (l >> 4) * 8;

  auto stage = [&](int kt, int buf) {
    const int k0 = kt * 32;
#pragma unroll
    for (int is = 0; is < ISS_B; ++is) {
      int eo = is * 2048 + tid * 8;
      int r = eo >> 5, c = eo & 31;
      gload_lds16(B + (long long)(rn + r) * ldb + k0 + c, &sB[buf][eo]);
    }
#pragma unroll
    for (int is = 0; is < ISS_A; ++is) {
      int eo = is * 2048 + tid * 8;
      int r = eo >> 5, c = eo & 31;
      gload_lds16(A + (long long)(rm + r) * lda + k0 + c, &sA[buf][eo]);
    }
  };

  f32x4 acc[MREP][NREP] = {};

  stage(0, 0);
  for (int kt = 0; kt < nkt; ++kt) {
    __syncthreads();
    if (kt + 1 < nkt) stage(kt + 1, (kt + 1) & 1);
    const unsigned short* a0 = sA[kt & 1];
    const unsigned short* b0 = sB[kt & 1];
    bf16x8 af[MREP], bfr[NREP];
#pragma unroll
    for (int m = 0; m < MREP; ++m)
      af[m] = *(const bf16x8*)&a0[(wm + m * 16 + lr) * 32 + lc8];
#pragma unroll
    for (int n = 0; n < NREP; ++n)
      bfr[n] = *(const bf16x8*)&b0[(wn + n * 16 + lr) * 32 + lc8];
#pragma unroll
    for (int m = 0; m < MREP; ++m)
#pragma unroll
      for (int n = 0; n < NREP; ++n)
        acc[m][n] = __builtin_amdgcn_mfma_f32_16x16x32_bf16(af[m], bfr[n], acc[m][n], 0, 0, 0);
  }

  const int r0 = rm + wm + (l >> 4) * 4;
  const int c0 = rn + wn + lr;
#pragma unroll
  for (int n = 0; n < NREP; ++n) {
    const int cc = c0 + n * 16;
    const float badd = bias[cc];
#pragma unroll
    for (int m = 0; m < MREP; ++m)
#pragma unroll
      for (int i = 0; i < 4; ++i)
        C[(long long)(r0 + m * 16 + i) * ldc + cc] = acc[m][n][i] + badd;
  }
}

// Sum 8 bf16 split-K partial slices -> bf16 t (fp32 accumulate)
__global__ void reduce8(const ushort4* __restrict__ P, ushort4* __restrict__ t) {
  const int S = 4096 * 256 / 4;  // 262144 ushort4 per slice
  int i = blockIdx.x * 256 + threadIdx.x;
  float sx = 0, sy = 0, sz = 0, sw = 0;
#pragma unroll
  for (int z = 0; z < 8; ++z) {
    ushort4 v = P[i + z * S];
    sx += bf2f(v.x); sy += bf2f(v.y); sz += bf2f(v.z); sw += bf2f(v.w);
  }
  ushort4 o;
  o.x = f2bf(sx); o.y = f2bf(sy); o.z = f2bf(sz); o.w = f2bf(sw);
  t[i] = o;
}

extern "C" void kernel_launch(void* const* d_in, const int* in_sizes, int n_in,
                              void* d_out, int out_size, void* d_ws, size_t ws_size,
                              hipStream_t stream) {
  const float* x    = (const float*)d_in[0];  // [4096,4096]
  const float* U    = (const float*)d_in[1];  // [256,4096]
  const float* V    = (const float*)d_in[2];  // [4096,256]
  const float* bias = (const float*)d_in[3];  // [4096]
  float* out = (float*)d_out;                 // [4096,4096] fp32

  // Workspace layout (22 MB):
  //  [0,16MB)   P: bf16 split-K partials [8][4096][256]
  //  [16,18MB)  t bf16 [4096][256]
  //  [18,20MB)  U bf16 [256][4096]
  //  [20,22MB)  V bf16 [4096][256]
  char* ws = (char*)d_ws;
  unsigned short* P   = (unsigned short*)ws;
  unsigned short* tb  = (unsigned short*)(ws + (16u << 20));
  unsigned short* Ub  = (unsigned short*)(ws + (18u << 20));
  unsigned short* Vb  = (unsigned short*)(ws + (20u << 20));

  castUV<<<2048, 256, 0, stream>>>((const float4*)U, (const float4*)V,
                                   (ushort4*)Ub, (ushort4*)Vb);

  // GEMM1: grid 64 M-blocks x 8 split-K, 512 blocks (2/CU), NKT=16 steps.
  dim3 g1(4096 / 64, 1, 8);
  gemm1_pipe<16><<<g1, 256, 0, stream>>>(x, Ub, P);

  reduce8<<<(4096 * 256 / 4) / 256, 256, 0, stream>>>((const ushort4*)P, (ushort4*)tb);

  // GEMM2: out = t @ V^T + bias. BM=BN=128, grid 32x32, fp32 out.
  dim3 g2(4096 / 128, 4096 / 128, 1);
  gemm_nt<4, 4><<<g2, 256, 0, stream>>>(tb, Vb, bias, out, 256, 256, 4096, 8);
}